// Round 3
// baseline (436.994 us; speedup 1.0000x reference)
//
#include <hip/hip_runtime.h>
#include <hip/hip_bf16.h>
#include <cstdint>
#include <cstddef>

#define NN     8192
#define INF_   256
#define OUTF   128
#define ALPHA  0.2f
#define LOG2E  1.4426950408889634f
#define JSPLIT 16
#define CHUNK  (NN / JSPLIT)     // 512 j per block
#define NS     (CHUNK / 32)      // 16 steps of 32 j

typedef __bf16 bf16;
typedef unsigned int u32;
typedef unsigned long long u64;
typedef __attribute__((ext_vector_type(8))) __bf16 bf16x8;
typedef __attribute__((ext_vector_type(4))) float f32x4;
typedef __attribute__((ext_vector_type(4))) int i32x4;
typedef __attribute__((ext_vector_type(4))) unsigned int u32x4;
typedef __attribute__((ext_vector_type(8))) unsigned short u16x8;
typedef __attribute__((ext_vector_type(4))) unsigned short u16x4;

// ---------------------------------------------------------------------------
// Dtype detector: read x's first 2048 uint16s as bf16. fp32 storage -> words
// are fp32 mantissa fragments -> huge exponents; bf16 storage -> N(0,1).
// flag = 1 -> tensors are fp32 (confirmed R2-R7); 0 -> bf16.
// ---------------------------------------------------------------------------
__global__ void gat_detect(const unsigned short* __restrict__ xr, int* __restrict__ flag)
{
    const int lane = threadIdx.x & 63;
    float m = 0.f;
    #pragma unroll
    for (int t = 0; t < 32; ++t) {
        const unsigned short u = xr[lane * 32 + t];
        const float v = fabsf((float)__builtin_bit_cast(bf16, u));
        if (v == v) m = fmaxf(m, v);
    }
    #pragma unroll
    for (int d = 1; d < 64; d <<= 1) m = fmaxf(m, __shfl_xor(m, d));
    if (lane == 0) *flag = (m > 100.f) ? 1 : 0;
}

// ---------------------------------------------------------------------------
// adj -> bitmask pre-pass. PURE stream: reads 256 MB coalesced at fill-like
// BW (~6.7 TB/s proven by the poison fills), writes 8 MB of packed bits.
// One wave per row; per iter 4 coalesced dword loads (j = it*256 + t*64 +
// lane) + 4 ballots (bit i = lane i = j offset) -> 4 u64. Ballot results are
// wave-uniform, so lanes 0..3 each pick one via a cndmask chain (no runtime-
// indexed array -> no scratch) and store. Natural little-endian bit order:
// dword (row*256 + j/32) holds bits j..j+31.
// ---------------------------------------------------------------------------
__global__ __launch_bounds__(256, 8)
void gat_pack(const int* __restrict__ adj, u64* __restrict__ P64)
{
    const int row  = (blockIdx.x * 256 + threadIdx.x) >> 6;   // 0..8191
    const int lane = threadIdx.x & 63;
    const int* rp = adj + (size_t)row * NN;
    u64* wp = P64 + (size_t)row * (NN / 64);
    #pragma unroll 4
    for (int it = 0; it < NN / 256; ++it) {   // 32 iters x 256 j
        int v0 = rp[it * 256 +   0 + lane];
        int v1 = rp[it * 256 +  64 + lane];
        int v2 = rp[it * 256 + 128 + lane];
        int v3 = rp[it * 256 + 192 + lane];
        const u64 b0 = __ballot(v0 != 0);
        const u64 b1 = __ballot(v1 != 0);
        const u64 b2 = __ballot(v2 != 0);
        const u64 b3 = __ballot(v3 != 0);
        u64 x = b0;
        if (lane == 1) x = b1;
        if (lane == 2) x = b2;
        if (lane == 3) x = b3;
        if (lane < 4) wp[it * 4 + lane] = x;
    }
}

// dtype-generic helpers ------------------------------------------------------
static __device__ __forceinline__ bf16  loadS(const bf16* p)  { return *p; }
static __device__ __forceinline__ bf16  loadS(const float* p) { return (bf16)*p; }
static __device__ __forceinline__ float loadF(const bf16* p)  { return (float)*p; }
static __device__ __forceinline__ float loadF(const float* p) { return *p; }
static __device__ __forceinline__ void load4(const float* p, bf16* d) {
    const f32x4 v = *(const f32x4*)p;
    #pragma unroll
    for (int t = 0; t < 4; ++t) d[t] = (bf16)v[t];
}
static __device__ __forceinline__ void load4(const bf16* p, bf16* d) {
    *(u16x4*)d = *(const u16x4*)p;
}

// async global->LDS, 16 B per lane (dest = wave-uniform base + lane*16)
typedef __attribute__((address_space(1))) const unsigned int gas_u32;
typedef __attribute__((address_space(3))) unsigned int las_u32;
static __device__ __forceinline__ void gll16(const void* g, void* l)
{
    __builtin_amdgcn_global_load_lds((gas_u32*)g, (las_u32*)l, 16, 0, 0);
}

// ---------------------------------------------------------------------------
// trans transpose: TT[n][k] = bf16(trans[k][n]).
// ---------------------------------------------------------------------------
template <typename T, int WANT>
__global__ void gat_tt(const T* __restrict__ trans, const int* __restrict__ flag,
                       bf16* __restrict__ TT)
{
    if (*flag != WANT) return;
    const int n = blockIdx.x;      // 0..127
    const int k = threadIdx.x;     // 0..255
    TT[n * INF_ + k] = loadS(trans + k * OUTF + n);
}

// ---------------------------------------------------------------------------
// Projection: h = x @ trans via LDS-staged MFMA. Outputs:
//   HTt tiled: HTt[i>>5][n][i&31]  (attn b-frag loads become contiguous 1KB)
//   e1c/e2c (pre-scaled by log2e)
// ---------------------------------------------------------------------------
template <typename T, int WANT>
__global__ __launch_bounds__(256, 1)
void gat_proj_t(const T* __restrict__ x, const bf16* __restrict__ TT,
                const T* __restrict__ aw, const int* __restrict__ flag,
                bf16* __restrict__ HTt, float* __restrict__ e1c, float* __restrict__ e2c)
{
    if (*flag != WANT) return;

    __shared__ bf16  xs[32][264];
    __shared__ bf16  TTs[128][264];
    __shared__ float hl[32][129];

    const int tid  = threadIdx.x;
    const int wave = tid >> 6;
    const int lane = tid & 63;
    const int m    = lane & 15;
    const int q    = lane >> 4;
    const int i0   = blockIdx.x * 32;

    #pragma unroll
    for (int it = 0; it < 8; ++it) {
        const int e = it * 1024 + tid * 4;
        bf16 tmp[4];
        load4(x + (size_t)i0 * INF_ + e, tmp);
        *(u16x4*)&xs[e >> 8][e & 255] = *(u16x4*)tmp;
    }
    #pragma unroll
    for (int it = 0; it < 16; ++it) {
        const int e = it * 2048 + tid * 8;
        *(u16x8*)&TTs[e >> 8][e & 255] = *(const u16x8*)(TT + e);
    }
    __syncthreads();

    const int rh = wave & 1, fh = wave >> 1;
    f32x4 acc[4] = {};
    #pragma unroll
    for (int ks = 0; ks < INF_; ks += 32) {
        const bf16x8 a = *(const bf16x8*)&xs[rh * 16 + m][ks + q * 8];
        #pragma unroll
        for (int tn = 0; tn < 4; ++tn) {
            const bf16x8 b = *(const bf16x8*)&TTs[fh * 64 + tn * 16 + m][ks + q * 8];
            acc[tn] = __builtin_amdgcn_mfma_f32_16x16x32_bf16(a, b, acc[tn], 0, 0, 0);
        }
    }

    #pragma unroll
    for (int tn = 0; tn < 4; ++tn)
        #pragma unroll
        for (int r = 0; r < 4; ++r)
            hl[rh * 16 + q * 4 + r][fh * 64 + tn * 16 + m] = acc[tn][r];
    __syncthreads();

    {   // e1/e2
        const int r = tid >> 3, seg = tid & 7;
        float s1 = 0.f, s2 = 0.f;
        #pragma unroll
        for (int u = 0; u < 16; ++u) {
            const float hv = hl[r][seg * 16 + u];
            s1 += hv * loadF(aw + seg * 16 + u);
            s2 += hv * loadF(aw + OUTF + seg * 16 + u);
        }
        #pragma unroll
        for (int d = 1; d < 8; d <<= 1) {
            s1 += __shfl_xor(s1, d);
            s2 += __shfl_xor(s2, d);
        }
        if (seg == 0) {
            e1c[i0 + r] = s1 * LOG2E;
            e2c[i0 + r] = s2 * LOG2E;
        }
    }

    {   // HTt tiled write
        const int n = tid >> 1, ih = tid & 1;
        u16x8 p0, p1;
        #pragma unroll
        for (int v = 0; v < 8; ++v) {
            p0[v] = __builtin_bit_cast(unsigned short, (bf16)hl[ih * 16 + v][n]);
            p1[v] = __builtin_bit_cast(unsigned short, (bf16)hl[ih * 16 + 8 + v][n]);
        }
        bf16* base = HTt + (size_t)blockIdx.x * 4096 + n * 32 + ih * 16;
        *(u16x8*)base       = p0;
        *(u16x8*)(base + 8) = p1;
    }
}

// ---------------------------------------------------------------------------
// Masked-softmax-attention partials, v4: adj mask now comes from the packed
// bitmask (8 MB total; 8 KB per block, L1-resident after first touch).
// R2 residue diagnosis: per-step vmcnt(0) drain waited on ~900-cy HBM adj
// loads with only ~350 cy of compute cover -> latency-exposed. Now the only
// per-step VMEM is 2 L2-hot gll tiles + 2 L1-hot mask dwords, so the drain
// is cheap and the kernel approaches its numP/compute floor.
// Per step, lane (m,q) needs mask bits for row (rbase+rg*16+m),
// j = jc*512 + s*32 + q*8 .. +8 -> bits (q*8..q*8+7) of dword
// pk[row*256 + jc*16 + s]. Dist-1 register prefetch.
// ---------------------------------------------------------------------------
__global__ __launch_bounds__(256, 4)
void gat_attn(const u32* __restrict__ pk, const bf16* __restrict__ HTt,
              const float* __restrict__ e1c, const float* __restrict__ e2c,
              float* __restrict__ numP, float* __restrict__ denP)
{
    __shared__ bf16  hts[2][4096];   // 2 x 8 KB HT step tiles
    __shared__ float e2s[CHUNK];     // 2 KB e2 slice (pre-scaled by log2e)

    const int tid  = threadIdx.x;
    const int wave = tid >> 6;
    const int lane = tid & 63;
    const int m    = lane & 15;
    const int q    = lane >> 4;
    const int jc   = blockIdx.x & (JSPLIT - 1);
    const int ig   = blockIdx.x / JSPLIT;
    const int rbase = ig * 128 + wave * 32;   // 2 row-groups: +0..15, +16..31
    const int j0    = jc * CHUNK;

    // HT staging geometry (unchanged from v3)
    const int hn = tid & 127;
    const int hq = tid >> 7;
    const bf16* tbase = HTt + (size_t)(jc * NS) * 4096;

    auto stageHT = [&](int s, int b) {
        const bf16* ts = tbase + (size_t)s * 4096;
        gll16(ts + hn * 32 + hq * 8,       &hts[b][(wave * 64) * 8]);
        gll16(ts + hn * 32 + (hq + 2) * 8, &hts[b][(256 + wave * 64) * 8]);
    };

    const float e1a = e1c[rbase + m];
    const float e1b = e1c[rbase + 16 + m];
    const u32* bp0 = pk + (size_t)(rbase + m) * (NN / 32) + jc * NS;
    const u32* bp1 = pk + (size_t)(rbase + 16 + m) * (NN / 32) + jc * NS;

    f32x4 acc0[8] = {};
    f32x4 acc1[8] = {};
    float rs0 = 0.f, rs1 = 0.f;

    // ---- prologue: tile 0 + mask dwords 0 in flight, e2 slice to LDS
    stageHT(0, 0);
    u32 w0 = bp0[0];
    u32 w1 = bp1[0];
    {
        const float2 ev = *(const float2*)(e2c + j0 + tid * 2);
        *(float2*)&e2s[tid * 2] = ev;
    }
    __syncthreads();   // drains vmcnt(0): tile 0 + masks ready

    #pragma unroll
    for (int s = 0; s < NS; ++s) {
        const int cur = s & 1;

        u32 w0n = w0, w1n = w1;
        if (s + 1 < NS) {
            // issue next HT tile + next mask dwords first: completion covered
            // by this step's compute + the end-of-step drain
            stageHT(s + 1, cur ^ 1);
            w0n = bp0[s + 1];
            w1n = bp1[s + 1];
        }

        const f32x4 e2a = *(const f32x4*)&e2s[s * 32 + q * 8];
        const f32x4 e2b = *(const f32x4*)&e2s[s * 32 + q * 8 + 4];

        bf16x8 af0, af1;   // A[m][k=q*8+t], leaky-relu in log2 domain, masked
        #pragma unroll
        for (int t = 0; t < 4; ++t) {
            float sv0 = e1a + e2a[t];
            sv0 = fmaxf(sv0, ALPHA * sv0);
            const float p0 = ((w0 >> (q * 8 + t)) & 1u) ? __builtin_amdgcn_exp2f(sv0) : 0.f;
            rs0 += p0; af0[t] = (bf16)p0;

            float sv1 = e1b + e2a[t];
            sv1 = fmaxf(sv1, ALPHA * sv1);
            const float p1 = ((w1 >> (q * 8 + t)) & 1u) ? __builtin_amdgcn_exp2f(sv1) : 0.f;
            rs1 += p1; af1[t] = (bf16)p1;
        }
        #pragma unroll
        for (int t = 0; t < 4; ++t) {
            float sv0 = e1a + e2b[t];
            sv0 = fmaxf(sv0, ALPHA * sv0);
            const float p0 = ((w0 >> (q * 8 + 4 + t)) & 1u) ? __builtin_amdgcn_exp2f(sv0) : 0.f;
            rs0 += p0; af0[4 + t] = (bf16)p0;

            float sv1 = e1b + e2b[t];
            sv1 = fmaxf(sv1, ALPHA * sv1);
            const float p1 = ((w1 >> (q * 8 + 4 + t)) & 1u) ? __builtin_amdgcn_exp2f(sv1) : 0.f;
            rs1 += p1; af1[4 + t] = (bf16)p1;
        }

        // 16 MFMAs: 8 shared b-frags from LDS serve both row-groups
        #pragma unroll
        for (int t = 0; t < 8; ++t) {
            const bf16x8 b = *(const bf16x8*)&hts[cur][q * 1024 + (t * 16 + m) * 8];
            acc0[t] = __builtin_amdgcn_mfma_f32_16x16x32_bf16(af0, b, acc0[t], 0, 0, 0);
            acc1[t] = __builtin_amdgcn_mfma_f32_16x16x32_bf16(af1, b, acc1[t], 0, 0, 0);
        }

        w0 = w0n; w1 = w1n;
        if (s + 1 < NS) __syncthreads();   // vmcnt(0)+barrier: next tile ready
    }

    // row-sums: lanes {m, m+16, m+32, m+48} hold the 4 q-slices of row m
    rs0 += __shfl_xor(rs0, 16);
    rs0 += __shfl_xor(rs0, 32);
    rs1 += __shfl_xor(rs1, 16);
    rs1 += __shfl_xor(rs1, 32);
    if (lane < 16) {
        denP[(size_t)jc * NN + rbase + m]      = rs0;
        denP[(size_t)jc * NN + rbase + 16 + m] = rs1;
    }

    // C/D layout: col = lane&15, row = q*4 + r -> unique partial slot
    #pragma unroll
    for (int t = 0; t < 8; ++t)
        #pragma unroll
        for (int r = 0; r < 4; ++r) {
            numP[((size_t)jc * NN + rbase + q * 4 + r) * OUTF + t * 16 + m]      = acc0[t][r];
            numP[((size_t)jc * NN + rbase + 16 + q * 4 + r) * OUTF + t * 16 + m] = acc1[t][r];
        }
}

// ---------------------------------------------------------------------------
// Finalize: out = elu( (sum_s numP) / (sum_s denP) )
// ---------------------------------------------------------------------------
__global__ __launch_bounds__(256)
void gat_fin(const float* __restrict__ numP, const float* __restrict__ denP,
             const int* __restrict__ flag, void* __restrict__ outv)
{
    const int g  = blockIdx.x * 256 + threadIdx.x;   // one thread per 4 elems
    const int i  = g >> 5;
    const int c4 = g & 31;
    float d = 0.f;
    f32x4 v = {0.f, 0.f, 0.f, 0.f};
    #pragma unroll
    for (int s = 0; s < JSPLIT; ++s) {
        d += denP[(size_t)s * NN + i];
        const f32x4 u = *(const f32x4*)(numP + ((size_t)s * NN + i) * OUTF + c4 * 4);
        #pragma unroll
        for (int t = 0; t < 4; ++t) v[t] += u[t];
    }
    #pragma unroll
    for (int t = 0; t < 4; ++t) {
        const float u = v[t] / d;
        v[t] = (u > 0.f) ? u : __builtin_amdgcn_exp2f(u * LOG2E) - 1.f;  // elu
    }
    const size_t off = (size_t)i * OUTF + c4 * 4;
    if (*flag) {
        *(f32x4*)((float*)outv + off) = v;
    } else {
        u16x4 pk;
        #pragma unroll
        for (int t = 0; t < 4; ++t)
            pk[t] = __builtin_bit_cast(unsigned short, (bf16)v[t]);
        *(u16x4*)((__hip_bfloat16*)outv + off) = pk;
    }
}

// ---------------------------------------------------------------------------
extern "C" void kernel_launch(void* const* d_in, const int* in_sizes, int n_in,
                              void* d_out, int out_size, void* d_ws, size_t ws_size,
                              hipStream_t stream)
{
    const int* adj = (const int*)d_in[1];

    // ws layout (bytes):
    // HTt 2MB | e1c 32KB | e2c 32KB | flag 256B | TT 64KB | numP 64MB |
    // denP 512KB | P64 8MB     (ws_size = 1 GiB per the poison-fill size)
    char* w = (char*)d_ws;
    bf16*  HTt   = (bf16*)w;   w += (size_t)OUTF * NN * 2;
    float* e1c   = (float*)w;  w += NN * 4;
    float* e2c   = (float*)w;  w += NN * 4;
    int*   flag  = (int*)w;    w += 256;
    bf16*  TT    = (bf16*)w;   w += (size_t)OUTF * INF_ * 2;
    float* numP  = (float*)w;  w += (size_t)JSPLIT * NN * OUTF * 4;
    float* denP  = (float*)w;  w += (size_t)JSPLIT * NN * 4;
    u64*   P64   = (u64*)w;

    gat_detect<<<1, 64, 0, stream>>>((const unsigned short*)d_in[0], flag);

    gat_pack<<<NN / 4, 256, 0, stream>>>(adj, P64);

    gat_tt<float, 1><<<OUTF, INF_, 0, stream>>>((const float*)d_in[2], flag, TT);
    gat_tt<bf16, 0><<<OUTF, INF_, 0, stream>>>((const bf16*)d_in[2], flag, TT);

    gat_proj_t<float, 1><<<NN / 32, 256, 0, stream>>>(
        (const float*)d_in[0], TT, (const float*)d_in[3], flag, HTt, e1c, e2c);
    gat_proj_t<bf16, 0><<<NN / 32, 256, 0, stream>>>(
        (const bf16*)d_in[0], TT, (const bf16*)d_in[3], flag, HTt, e1c, e2c);

    gat_attn<<<(NN / 128) * JSPLIT, 256, 0, stream>>>(
        (const u32*)P64, HTt, e1c, e2c, numP, denP);

    gat_fin<<<NN * OUTF / 4 / 256, 256, 0, stream>>>(numP, denP, flag, d_out);
}

// Round 4
// 425.598 us; speedup vs baseline: 1.0268x; 1.0268x over previous
//
#include <hip/hip_runtime.h>
#include <hip/hip_bf16.h>
#include <cstdint>
#include <cstddef>

#define NN     8192
#define INF_   256
#define OUTF   128
#define ALPHA  0.2f
#define LOG2E  1.4426950408889634f
#define JSPLIT 16
#define CHUNK  (NN / JSPLIT)     // 512 j per block
#define NS     (CHUNK / 32)      // 16 steps of 32 j

typedef __bf16 bf16;
typedef unsigned int u32;
typedef unsigned long long u64;
typedef __attribute__((ext_vector_type(8))) __bf16 bf16x8;
typedef __attribute__((ext_vector_type(4))) float f32x4;
typedef __attribute__((ext_vector_type(4))) int i32x4;
typedef __attribute__((ext_vector_type(4))) unsigned int u32x4;
typedef __attribute__((ext_vector_type(8))) unsigned short u16x8;
typedef __attribute__((ext_vector_type(4))) unsigned short u16x4;

// ---------------------------------------------------------------------------
// Dtype detector: read x's first 2048 uint16s as bf16. fp32 storage -> words
// are fp32 mantissa fragments -> huge exponents; bf16 storage -> N(0,1).
// flag = 1 -> tensors are fp32 (confirmed R2-R7); 0 -> bf16.
// ---------------------------------------------------------------------------
__global__ void gat_detect(const unsigned short* __restrict__ xr, int* __restrict__ flag)
{
    const int lane = threadIdx.x & 63;
    float m = 0.f;
    #pragma unroll
    for (int t = 0; t < 32; ++t) {
        const unsigned short u = xr[lane * 32 + t];
        const float v = fabsf((float)__builtin_bit_cast(bf16, u));
        if (v == v) m = fmaxf(m, v);
    }
    #pragma unroll
    for (int d = 1; d < 64; d <<= 1) m = fmaxf(m, __shfl_xor(m, d));
    if (lane == 0) *flag = (m > 100.f) ? 1 : 0;
}

// dtype-generic helpers ------------------------------------------------------
static __device__ __forceinline__ bf16  loadS(const bf16* p)  { return *p; }
static __device__ __forceinline__ bf16  loadS(const float* p) { return (bf16)*p; }
static __device__ __forceinline__ float loadF(const bf16* p)  { return (float)*p; }
static __device__ __forceinline__ float loadF(const float* p) { return *p; }
static __device__ __forceinline__ void load4(const float* p, bf16* d) {
    const f32x4 v = *(const f32x4*)p;
    #pragma unroll
    for (int t = 0; t < 4; ++t) d[t] = (bf16)v[t];
}
static __device__ __forceinline__ void load4(const bf16* p, bf16* d) {
    *(u16x4*)d = *(const u16x4*)p;
}

// async global->LDS, 16 B per lane (dest = wave-uniform base + lane*16)
typedef __attribute__((address_space(1))) const unsigned int gas_u32;
typedef __attribute__((address_space(3))) unsigned int las_u32;
static __device__ __forceinline__ void gll16(const void* g, void* l)
{
    __builtin_amdgcn_global_load_lds((gas_u32*)g, (las_u32*)l, 16, 0, 0);
}

// ---------------------------------------------------------------------------
// trans transpose: TT[n][k] = bf16(trans[k][n]).
// ---------------------------------------------------------------------------
template <typename T, int WANT>
__global__ void gat_tt(const T* __restrict__ trans, const int* __restrict__ flag,
                       bf16* __restrict__ TT)
{
    if (*flag != WANT) return;
    const int n = blockIdx.x;      // 0..127
    const int k = threadIdx.x;     // 0..255
    TT[n * INF_ + k] = loadS(trans + k * OUTF + n);
}

// ---------------------------------------------------------------------------
// Projection: h = x @ trans via LDS-staged MFMA. Outputs:
//   HTt tiled: HTt[i>>5][n][i&31]  (attn b-frag loads become contiguous 1KB)
//   e1c/e2c (pre-scaled by log2e)
// ---------------------------------------------------------------------------
template <typename T, int WANT>
__global__ __launch_bounds__(256, 1)
void gat_proj_t(const T* __restrict__ x, const bf16* __restrict__ TT,
                const T* __restrict__ aw, const int* __restrict__ flag,
                bf16* __restrict__ HTt, float* __restrict__ e1c, float* __restrict__ e2c)
{
    if (*flag != WANT) return;

    __shared__ bf16  xs[32][264];
    __shared__ bf16  TTs[128][264];
    __shared__ float hl[32][129];

    const int tid  = threadIdx.x;
    const int wave = tid >> 6;
    const int lane = tid & 63;
    const int m    = lane & 15;
    const int q    = lane >> 4;
    const int i0   = blockIdx.x * 32;

    #pragma unroll
    for (int it = 0; it < 8; ++it) {
        const int e = it * 1024 + tid * 4;
        bf16 tmp[4];
        load4(x + (size_t)i0 * INF_ + e, tmp);
        *(u16x4*)&xs[e >> 8][e & 255] = *(u16x4*)tmp;
    }
    #pragma unroll
    for (int it = 0; it < 16; ++it) {
        const int e = it * 2048 + tid * 8;
        *(u16x8*)&TTs[e >> 8][e & 255] = *(const u16x8*)(TT + e);
    }
    __syncthreads();

    const int rh = wave & 1, fh = wave >> 1;
    f32x4 acc[4] = {};
    #pragma unroll
    for (int ks = 0; ks < INF_; ks += 32) {
        const bf16x8 a = *(const bf16x8*)&xs[rh * 16 + m][ks + q * 8];
        #pragma unroll
        for (int tn = 0; tn < 4; ++tn) {
            const bf16x8 b = *(const bf16x8*)&TTs[fh * 64 + tn * 16 + m][ks + q * 8];
            acc[tn] = __builtin_amdgcn_mfma_f32_16x16x32_bf16(a, b, acc[tn], 0, 0, 0);
        }
    }

    #pragma unroll
    for (int tn = 0; tn < 4; ++tn)
        #pragma unroll
        for (int r = 0; r < 4; ++r)
            hl[rh * 16 + q * 4 + r][fh * 64 + tn * 16 + m] = acc[tn][r];
    __syncthreads();

    {   // e1/e2
        const int r = tid >> 3, seg = tid & 7;
        float s1 = 0.f, s2 = 0.f;
        #pragma unroll
        for (int u = 0; u < 16; ++u) {
            const float hv = hl[r][seg * 16 + u];
            s1 += hv * loadF(aw + seg * 16 + u);
            s2 += hv * loadF(aw + OUTF + seg * 16 + u);
        }
        #pragma unroll
        for (int d = 1; d < 8; d <<= 1) {
            s1 += __shfl_xor(s1, d);
            s2 += __shfl_xor(s2, d);
        }
        if (seg == 0) {
            e1c[i0 + r] = s1 * LOG2E;
            e2c[i0 + r] = s2 * LOG2E;
        }
    }

    {   // HTt tiled write
        const int n = tid >> 1, ih = tid & 1;
        u16x8 p0, p1;
        #pragma unroll
        for (int v = 0; v < 8; ++v) {
            p0[v] = __builtin_bit_cast(unsigned short, (bf16)hl[ih * 16 + v][n]);
            p1[v] = __builtin_bit_cast(unsigned short, (bf16)hl[ih * 16 + 8 + v][n]);
        }
        bf16* base = HTt + (size_t)blockIdx.x * 4096 + n * 32 + ih * 16;
        *(u16x8*)base       = p0;
        *(u16x8*)(base + 8) = p1;
    }
}

// ---------------------------------------------------------------------------
// Masked-softmax-attention partials, v5: max-occupancy form.
// R3 post-mortem: pack pre-pass was net-negative (adj stream in-kernel was
// NOT the main exposure); attn residue is latency/sync structure at only
// 4 blocks/CU (RG=2 needs ~100+ VGPR). v5: RG=1 (acc = 32 VGPR, live ~60),
// __launch_bounds__(256,8) -> 8 blocks/CU, 32 waves/CU. Per step, per wave:
// 2 adj dwordx4 (HBM, no reg-prefetch: 8 waves/SIMD TLP covers ~900 cy),
// 2 gll16 (next tile, L2-hot), 8 b-frag ds_read_b128 from the LDS tile
// shared by all 4 waves, 8 MFMAs. LDS 18 KB x 8 blocks = 144 KB/CU.
// adj loads issued BEFORE stageHT so their mid-step wait doesn't imply a
// gll drain; step-end __syncthreads (vmcnt(0)) is the tile-ready barrier.
// ---------------------------------------------------------------------------
__global__ __launch_bounds__(256, 8)
void gat_attn(const int* __restrict__ adj, const bf16* __restrict__ HTt,
              const float* __restrict__ e1c, const float* __restrict__ e2c,
              float* __restrict__ numP, float* __restrict__ denP)
{
    __shared__ bf16  hts[2][4096];   // 2 x 8 KB HT step tiles
    __shared__ float e2s[CHUNK];     // 2 KB e2 slice (pre-scaled by log2e)

    const int tid  = threadIdx.x;
    const int wave = tid >> 6;
    const int lane = tid & 63;
    const int m    = lane & 15;
    const int q    = lane >> 4;
    const int jc   = blockIdx.x & (JSPLIT - 1);
    const int ig   = blockIdx.x / JSPLIT;
    const int rbase = ig * 64 + wave * 16;   // one 16-row group per wave
    const int j0    = jc * CHUNK;

    // HT staging geometry: dest = linear (base + lane*16); source address is
    // per-lane, chosen so hts[w*512 + l*8 + t] == tile[n = (w&1)*64 + l]
    //                                                 [jj = (w>>1)*8 + t]
    const int hn = tid & 127;
    const int hq = tid >> 7;
    const bf16* tbase = HTt + (size_t)(jc * NS) * 4096;

    auto stageHT = [&](int s, int b) {
        const bf16* ts = tbase + (size_t)s * 4096;
        gll16(ts + hn * 32 + hq * 8,       &hts[b][(wave * 64) * 8]);
        gll16(ts + hn * 32 + (hq + 2) * 8, &hts[b][(256 + wave * 64) * 8]);
    };

    const float e1 = e1c[rbase + m];
    // lane (m,q): row rbase+m, 8 consecutive j at q*8 within each 32-j step
    const int* ap = adj + (size_t)(rbase + m) * NN + j0 + q * 8;

    f32x4 acc[8] = {};
    float rs = 0.f;

    // ---- prologue: tile 0 in flight, e2 slice to LDS
    stageHT(0, 0);
    {
        const float2 ev = *(const float2*)(e2c + j0 + tid * 2);
        *(float2*)&e2s[tid * 2] = ev;
    }
    __syncthreads();   // drains vmcnt(0): tile 0 ready

    #pragma unroll
    for (int s = 0; s < NS; ++s) {
        const int cur = s & 1;

        // this step's adj (consumed mid-step; issued first so the wait on it
        // does not force the gll16s to drain early)
        const i32x4 va = *(const i32x4*)(ap + s * 32);
        const i32x4 vb = *(const i32x4*)(ap + s * 32 + 4);

        if (s + 1 < NS) stageHT(s + 1, cur ^ 1);   // next tile -> other buffer

        const f32x4 e2a = *(const f32x4*)&e2s[s * 32 + q * 8];
        const f32x4 e2b = *(const f32x4*)&e2s[s * 32 + q * 8 + 4];

        bf16x8 af;   // A[m][k=q*8+t], leaky-relu in log2 domain, adj-masked
        #pragma unroll
        for (int t = 0; t < 4; ++t) {
            float sv = e1 + e2a[t];
            sv = fmaxf(sv, ALPHA * sv);
            const float p = (va[t] != 0) ? __builtin_amdgcn_exp2f(sv) : 0.f;
            rs += p;
            af[t] = (bf16)p;
        }
        #pragma unroll
        for (int t = 0; t < 4; ++t) {
            float sv = e1 + e2b[t];
            sv = fmaxf(sv, ALPHA * sv);
            const float p = (vb[t] != 0) ? __builtin_amdgcn_exp2f(sv) : 0.f;
            rs += p;
            af[4 + t] = (bf16)p;
        }

        // 8 MFMAs vs the shared LDS tile
        #pragma unroll
        for (int t = 0; t < 8; ++t) {
            const bf16x8 b = *(const bf16x8*)&hts[cur][q * 1024 + (t * 16 + m) * 8];
            acc[t] = __builtin_amdgcn_mfma_f32_16x16x32_bf16(af, b, acc[t], 0, 0, 0);
        }

        if (s + 1 < NS) __syncthreads();   // vmcnt(0)+barrier: next tile ready
    }

    // row-sum: lanes {m, m+16, m+32, m+48} hold the 4 q-slices of row m
    rs += __shfl_xor(rs, 16);
    rs += __shfl_xor(rs, 32);
    if (lane < 16) denP[(size_t)jc * NN + rbase + m] = rs;

    // C/D layout: col = lane&15, row = q*4 + r -> unique partial slot
    #pragma unroll
    for (int t = 0; t < 8; ++t)
        #pragma unroll
        for (int r = 0; r < 4; ++r)
            numP[((size_t)jc * NN + rbase + q * 4 + r) * OUTF + t * 16 + m] = acc[t][r];
}

// ---------------------------------------------------------------------------
// Finalize: out = elu( (sum_s numP) / (sum_s denP) )
// ---------------------------------------------------------------------------
__global__ __launch_bounds__(256)
void gat_fin(const float* __restrict__ numP, const float* __restrict__ denP,
             const int* __restrict__ flag, void* __restrict__ outv)
{
    const int g  = blockIdx.x * 256 + threadIdx.x;   // one thread per 4 elems
    const int i  = g >> 5;
    const int c4 = g & 31;
    float d = 0.f;
    f32x4 v = {0.f, 0.f, 0.f, 0.f};
    #pragma unroll
    for (int s = 0; s < JSPLIT; ++s) {
        d += denP[(size_t)s * NN + i];
        const f32x4 u = *(const f32x4*)(numP + ((size_t)s * NN + i) * OUTF + c4 * 4);
        #pragma unroll
        for (int t = 0; t < 4; ++t) v[t] += u[t];
    }
    #pragma unroll
    for (int t = 0; t < 4; ++t) {
        const float u = v[t] / d;
        v[t] = (u > 0.f) ? u : __builtin_amdgcn_exp2f(u * LOG2E) - 1.f;  // elu
    }
    const size_t off = (size_t)i * OUTF + c4 * 4;
    if (*flag) {
        *(f32x4*)((float*)outv + off) = v;
    } else {
        u16x4 pk;
        #pragma unroll
        for (int t = 0; t < 4; ++t)
            pk[t] = __builtin_bit_cast(unsigned short, (bf16)v[t]);
        *(u16x4*)((__hip_bfloat16*)outv + off) = pk;
    }
}

// ---------------------------------------------------------------------------
extern "C" void kernel_launch(void* const* d_in, const int* in_sizes, int n_in,
                              void* d_out, int out_size, void* d_ws, size_t ws_size,
                              hipStream_t stream)
{
    const int* adj = (const int*)d_in[1];

    // ws layout (bytes):
    // HTt 2MB | e1c 32KB | e2c 32KB | flag 256B | TT 64KB | numP 64MB | denP 512KB
    char* w = (char*)d_ws;
    bf16*  HTt   = (bf16*)w;   w += (size_t)OUTF * NN * 2;
    float* e1c   = (float*)w;  w += NN * 4;
    float* e2c   = (float*)w;  w += NN * 4;
    int*   flag  = (int*)w;    w += 256;
    bf16*  TT    = (bf16*)w;   w += (size_t)OUTF * INF_ * 2;
    float* numP  = (float*)w;  w += (size_t)JSPLIT * NN * OUTF * 4;
    float* denP  = (float*)w;

    gat_detect<<<1, 64, 0, stream>>>((const unsigned short*)d_in[0], flag);

    gat_tt<float, 1><<<OUTF, INF_, 0, stream>>>((const float*)d_in[2], flag, TT);
    gat_tt<bf16, 0><<<OUTF, INF_, 0, stream>>>((const bf16*)d_in[2], flag, TT);

    gat_proj_t<float, 1><<<NN / 32, 256, 0, stream>>>(
        (const float*)d_in[0], TT, (const float*)d_in[3], flag, HTt, e1c, e2c);
    gat_proj_t<bf16, 0><<<NN / 32, 256, 0, stream>>>(
        (const bf16*)d_in[0], TT, (const bf16*)d_in[3], flag, HTt, e1c, e2c);

    gat_attn<<<(NN / 64) * JSPLIT, 256, 0, stream>>>(adj, HTt, e1c, e2c, numP, denP);

    gat_fin<<<NN * OUTF / 4 / 256, 256, 0, stream>>>(numP, denP, flag, d_out);
}

// Round 5
// 407.885 us; speedup vs baseline: 1.0714x; 1.0434x over previous
//
#include <hip/hip_runtime.h>
#include <hip/hip_bf16.h>
#include <cstdint>
#include <cstddef>

#define NN     8192
#define INF_   256
#define OUTF   128
#define ALPHA  0.2f
#define LOG2E  1.4426950408889634f
#define JSPLIT 16
#define CHUNK  (NN / JSPLIT)     // 512 j per block
#define NS     (CHUNK / 32)      // 16 steps of 32 j

typedef __bf16 bf16;
typedef unsigned int u32;
typedef unsigned long long u64;
typedef __attribute__((ext_vector_type(8))) __bf16 bf16x8;
typedef __attribute__((ext_vector_type(4))) float f32x4;
typedef __attribute__((ext_vector_type(4))) int i32x4;
typedef __attribute__((ext_vector_type(4))) unsigned int u32x4;
typedef __attribute__((ext_vector_type(8))) unsigned short u16x8;
typedef __attribute__((ext_vector_type(4))) unsigned short u16x4;

// ---------------------------------------------------------------------------
// Dtype detector: read x's first 2048 uint16s as bf16. fp32 storage -> words
// are fp32 mantissa fragments -> huge exponents; bf16 storage -> N(0,1).
// flag = 1 -> tensors are fp32 (confirmed R2-R7); 0 -> bf16.
// ---------------------------------------------------------------------------
__global__ void gat_detect(const unsigned short* __restrict__ xr, int* __restrict__ flag)
{
    const int lane = threadIdx.x & 63;
    float m = 0.f;
    #pragma unroll
    for (int t = 0; t < 32; ++t) {
        const unsigned short u = xr[lane * 32 + t];
        const float v = fabsf((float)__builtin_bit_cast(bf16, u));
        if (v == v) m = fmaxf(m, v);
    }
    #pragma unroll
    for (int d = 1; d < 64; d <<= 1) m = fmaxf(m, __shfl_xor(m, d));
    if (lane == 0) *flag = (m > 100.f) ? 1 : 0;
}

// dtype-generic helpers ------------------------------------------------------
static __device__ __forceinline__ bf16  loadS(const bf16* p)  { return *p; }
static __device__ __forceinline__ bf16  loadS(const float* p) { return (bf16)*p; }
static __device__ __forceinline__ float loadF(const bf16* p)  { return (float)*p; }
static __device__ __forceinline__ float loadF(const float* p) { return *p; }
static __device__ __forceinline__ void load4(const float* p, bf16* d) {
    const f32x4 v = *(const f32x4*)p;
    #pragma unroll
    for (int t = 0; t < 4; ++t) d[t] = (bf16)v[t];
}
static __device__ __forceinline__ void load4(const bf16* p, bf16* d) {
    *(u16x4*)d = *(const u16x4*)p;
}

// async global->LDS, 16 B per lane (dest = wave-uniform base + lane*16)
typedef __attribute__((address_space(1))) const unsigned int gas_u32;
typedef __attribute__((address_space(3))) unsigned int las_u32;
static __device__ __forceinline__ void gll16(const void* g, void* l)
{
    __builtin_amdgcn_global_load_lds((gas_u32*)g, (las_u32*)l, 16, 0, 0);
}

#define MEMFENCE asm volatile("" ::: "memory")

// ---------------------------------------------------------------------------
// trans transpose: TT[n][k] = bf16(trans[k][n]).
// ---------------------------------------------------------------------------
template <typename T, int WANT>
__global__ void gat_tt(const T* __restrict__ trans, const int* __restrict__ flag,
                       bf16* __restrict__ TT)
{
    if (*flag != WANT) return;
    const int n = blockIdx.x;      // 0..127
    const int k = threadIdx.x;     // 0..255
    TT[n * INF_ + k] = loadS(trans + k * OUTF + n);
}

// ---------------------------------------------------------------------------
// Projection: h = x @ trans via LDS-staged MFMA. Outputs:
//   HTt tiled: HTt[i>>5][n][i&31]  (attn b-frag loads become contiguous 1KB)
//   e1c/e2c (pre-scaled by log2e)
// ---------------------------------------------------------------------------
template <typename T, int WANT>
__global__ __launch_bounds__(256, 1)
void gat_proj_t(const T* __restrict__ x, const bf16* __restrict__ TT,
                const T* __restrict__ aw, const int* __restrict__ flag,
                bf16* __restrict__ HTt, float* __restrict__ e1c, float* __restrict__ e2c)
{
    if (*flag != WANT) return;

    __shared__ bf16  xs[32][264];
    __shared__ bf16  TTs[128][264];
    __shared__ float hl[32][129];

    const int tid  = threadIdx.x;
    const int wave = tid >> 6;
    const int lane = tid & 63;
    const int m    = lane & 15;
    const int q    = lane >> 4;
    const int i0   = blockIdx.x * 32;

    #pragma unroll
    for (int it = 0; it < 8; ++it) {
        const int e = it * 1024 + tid * 4;
        bf16 tmp[4];
        load4(x + (size_t)i0 * INF_ + e, tmp);
        *(u16x4*)&xs[e >> 8][e & 255] = *(u16x4*)tmp;
    }
    #pragma unroll
    for (int it = 0; it < 16; ++it) {
        const int e = it * 2048 + tid * 8;
        *(u16x8*)&TTs[e >> 8][e & 255] = *(const u16x8*)(TT + e);
    }
    __syncthreads();

    const int rh = wave & 1, fh = wave >> 1;
    f32x4 acc[4] = {};
    #pragma unroll
    for (int ks = 0; ks < INF_; ks += 32) {
        const bf16x8 a = *(const bf16x8*)&xs[rh * 16 + m][ks + q * 8];
        #pragma unroll
        for (int tn = 0; tn < 4; ++tn) {
            const bf16x8 b = *(const bf16x8*)&TTs[fh * 64 + tn * 16 + m][ks + q * 8];
            acc[tn] = __builtin_amdgcn_mfma_f32_16x16x32_bf16(a, b, acc[tn], 0, 0, 0);
        }
    }

    #pragma unroll
    for (int tn = 0; tn < 4; ++tn)
        #pragma unroll
        for (int r = 0; r < 4; ++r)
            hl[rh * 16 + q * 4 + r][fh * 64 + tn * 16 + m] = acc[tn][r];
    __syncthreads();

    {   // e1/e2
        const int r = tid >> 3, seg = tid & 7;
        float s1 = 0.f, s2 = 0.f;
        #pragma unroll
        for (int u = 0; u < 16; ++u) {
            const float hv = hl[r][seg * 16 + u];
            s1 += hv * loadF(aw + seg * 16 + u);
            s2 += hv * loadF(aw + OUTF + seg * 16 + u);
        }
        #pragma unroll
        for (int d = 1; d < 8; d <<= 1) {
            s1 += __shfl_xor(s1, d);
            s2 += __shfl_xor(s2, d);
        }
        if (seg == 0) {
            e1c[i0 + r] = s1 * LOG2E;
            e2c[i0 + r] = s2 * LOG2E;
        }
    }

    {   // HTt tiled write
        const int n = tid >> 1, ih = tid & 1;
        u16x8 p0, p1;
        #pragma unroll
        for (int v = 0; v < 8; ++v) {
            p0[v] = __builtin_bit_cast(unsigned short, (bf16)hl[ih * 16 + v][n]);
            p1[v] = __builtin_bit_cast(unsigned short, (bf16)hl[ih * 16 + 8 + v][n]);
        }
        bf16* base = HTt + (size_t)blockIdx.x * 4096 + n * 32 + ih * 16;
        *(u16x8*)base       = p0;
        *(u16x8*)(base + 8) = p1;
    }
}

// ---------------------------------------------------------------------------
// Masked-softmax-attention partials, v6: counted-vmcnt pipeline (T3/T4).
// R4 post-mortem: 8 blocks/CU (RG=1) == 4 blocks/CU (RG=2) == ~125-130 us,
// so the limiter is the per-step __syncthreads -> s_waitcnt vmcnt(0) drain:
// each block serially eats HBM adj latency every step, and any prefetch is
// drained by the very barrier that follows it. v6 keeps v5's shape but:
//   - 3 LDS tile buffers, gll16 staged at distance 2
//   - adj register prefetch at distance 2 (parity-indexed, full unroll)
//   - raw s_barrier + asm "s_waitcnt vmcnt(4)": per wave, per step, exactly
//     4 VMEM ops are issued (2 gll + 2 adj dwordx4); waiting all-but-4
//     guarantees step s+1's tile+adj are complete while s+2's 4 stay in
//     flight with ~2 full steps of compute cover (m218's counted-wait lever).
//   - asm ""::: "memory" fences pin each step's issue region so the per-wave
//     vmcnt sequencing is well-defined (loads cannot cross a may-write asm).
// __launch_bounds__(256,4): ~80 live VGPR << 128 cap (no spill), LDS 26 KB,
// grid 2048 = two even 4-blocks/CU passes.
// ---------------------------------------------------------------------------
__global__ __launch_bounds__(256, 4)
void gat_attn(const int* __restrict__ adj, const bf16* __restrict__ HTt,
              const float* __restrict__ e1c, const float* __restrict__ e2c,
              float* __restrict__ numP, float* __restrict__ denP)
{
    __shared__ bf16  hts[3][4096];   // 3 x 8 KB HT step tiles
    __shared__ float e2s[CHUNK];     // 2 KB e2 slice (pre-scaled by log2e)

    const int tid  = threadIdx.x;
    const int wave = tid >> 6;
    const int lane = tid & 63;
    const int m    = lane & 15;
    const int q    = lane >> 4;
    const int jc   = blockIdx.x & (JSPLIT - 1);
    const int ig   = blockIdx.x / JSPLIT;
    const int rbase = ig * 64 + wave * 16;   // one 16-row group per wave
    const int j0    = jc * CHUNK;

    const int hn = tid & 127;
    const int hq = tid >> 7;
    const bf16* tbase = HTt + (size_t)(jc * NS) * 4096;

    auto stageHT = [&](int s, int b) {
        const bf16* ts = tbase + (size_t)s * 4096;
        gll16(ts + hn * 32 + hq * 8,       &hts[b][(wave * 64) * 8]);
        gll16(ts + hn * 32 + (hq + 2) * 8, &hts[b][(256 + wave * 64) * 8]);
    };

    // e1/e2 first: their implicit waits happen before any counted staging
    const float e1 = e1c[rbase + m];
    {
        const float2 ev = *(const float2*)(e2c + j0 + tid * 2);
        *(float2*)&e2s[tid * 2] = ev;   // compiler waits its own load here
    }

    // lane (m,q): row rbase+m, 8 consecutive j at q*8 within each 32-j step
    const int* ap = adj + (size_t)(rbase + m) * NN + j0 + q * 8;

    f32x4 acc[8] = {};
    float rs = 0.f;
    i32x4 adjv[2][2];   // distance-2 adj prefetch, parity s&1

    // ---- prologue: steps 0 and 1 in flight (4 VMEM ops each, in order)
    stageHT(0, 0);
    adjv[0][0] = *(const i32x4*)(ap);
    adjv[0][1] = *(const i32x4*)(ap + 4);
    MEMFENCE;
    stageHT(1, 1);
    adjv[1][0] = *(const i32x4*)(ap + 32);
    adjv[1][1] = *(const i32x4*)(ap + 36);
    asm volatile("s_waitcnt vmcnt(4) lgkmcnt(0)" ::: "memory");  // step-0 set + e2s ready
    __builtin_amdgcn_s_barrier();
    MEMFENCE;

    #pragma unroll
    for (int s = 0; s < NS; ++s) {
        const int cur = s % 3;
        const int par = s & 1;

        // issue next-next tile first (2 gll): its buffer was last read in
        // step s-1, protected by the end-of-(s-1) barrier
        if (s < NS - 2) stageHT(s + 2, (s + 2) % 3);
        MEMFENCE;

        const f32x4 e2a = *(const f32x4*)&e2s[s * 32 + q * 8];
        const f32x4 e2b = *(const f32x4*)&e2s[s * 32 + q * 8 + 4];

        bf16x8 af;   // A[m][k=q*8+t], leaky-relu in log2 domain, adj-masked
        #pragma unroll
        for (int t = 0; t < 4; ++t) {
            float sv = e1 + e2a[t];
            sv = fmaxf(sv, ALPHA * sv);
            const float p = (adjv[par][0][t] != 0) ? __builtin_amdgcn_exp2f(sv) : 0.f;
            rs += p;
            af[t] = (bf16)p;
        }
        #pragma unroll
        for (int t = 0; t < 4; ++t) {
            float sv = e1 + e2b[t];
            sv = fmaxf(sv, ALPHA * sv);
            const float p = (adjv[par][1][t] != 0) ? __builtin_amdgcn_exp2f(sv) : 0.f;
            rs += p;
            af[4 + t] = (bf16)p;
        }

        // refill the parity slot just consumed with step s+2's adj (2 loads)
        if (s < NS - 2) {
            adjv[par][0] = *(const i32x4*)(ap + (s + 2) * 32);
            adjv[par][1] = *(const i32x4*)(ap + (s + 2) * 32 + 4);
        }

        // 8 MFMAs vs the shared LDS tile (compiler handles lgkm for ds_reads)
        #pragma unroll
        for (int t = 0; t < 8; ++t) {
            const bf16x8 b = *(const bf16x8*)&hts[cur][q * 1024 + (t * 16 + m) * 8];
            acc[t] = __builtin_amdgcn_mfma_f32_16x16x32_bf16(af, b, acc[t], 0, 0, 0);
        }

        // counted wait: step s+1's 4 ops are "all but the newest 4"
        if (s < NS - 2) {
            asm volatile("s_waitcnt vmcnt(4)" ::: "memory");
            __builtin_amdgcn_s_barrier();
            MEMFENCE;
        } else if (s == NS - 2) {
            asm volatile("s_waitcnt vmcnt(0)" ::: "memory");
            __builtin_amdgcn_s_barrier();
            MEMFENCE;
        }
        // s == NS-1: no trailing barrier
    }

    // row-sum: lanes {m, m+16, m+32, m+48} hold the 4 q-slices of row m
    rs += __shfl_xor(rs, 16);
    rs += __shfl_xor(rs, 32);
    if (lane < 16) denP[(size_t)jc * NN + rbase + m] = rs;

    // C/D layout: col = lane&15, row = q*4 + r -> unique partial slot
    #pragma unroll
    for (int t = 0; t < 8; ++t)
        #pragma unroll
        for (int r = 0; r < 4; ++r)
            numP[((size_t)jc * NN + rbase + q * 4 + r) * OUTF + t * 16 + m] = acc[t][r];
}

// ---------------------------------------------------------------------------
// Finalize: out = elu( (sum_s numP) / (sum_s denP) )
// ---------------------------------------------------------------------------
__global__ __launch_bounds__(256)
void gat_fin(const float* __restrict__ numP, const float* __restrict__ denP,
             const int* __restrict__ flag, void* __restrict__ outv)
{
    const int g  = blockIdx.x * 256 + threadIdx.x;   // one thread per 4 elems
    const int i  = g >> 5;
    const int c4 = g & 31;
    float d = 0.f;
    f32x4 v = {0.f, 0.f, 0.f, 0.f};
    #pragma unroll
    for (int s = 0; s < JSPLIT; ++s) {
        d += denP[(size_t)s * NN + i];
        const f32x4 u = *(const f32x4*)(numP + ((size_t)s * NN + i) * OUTF + c4 * 4);
        #pragma unroll
        for (int t = 0; t < 4; ++t) v[t] += u[t];
    }
    #pragma unroll
    for (int t = 0; t < 4; ++t) {
        const float u = v[t] / d;
        v[t] = (u > 0.f) ? u : __builtin_amdgcn_exp2f(u * LOG2E) - 1.f;  // elu
    }
    const size_t off = (size_t)i * OUTF + c4 * 4;
    if (*flag) {
        *(f32x4*)((float*)outv + off) = v;
    } else {
        u16x4 pk;
        #pragma unroll
        for (int t = 0; t < 4; ++t)
            pk[t] = __builtin_bit_cast(unsigned short, (bf16)v[t]);
        *(u16x4*)((__hip_bfloat16*)outv + off) = pk;
    }
}

// ---------------------------------------------------------------------------
extern "C" void kernel_launch(void* const* d_in, const int* in_sizes, int n_in,
                              void* d_out, int out_size, void* d_ws, size_t ws_size,
                              hipStream_t stream)
{
    const int* adj = (const int*)d_in[1];

    // ws layout (bytes):
    // HTt 2MB | e1c 32KB | e2c 32KB | flag 256B | TT 64KB | numP 64MB | denP 512KB
    char* w = (char*)d_ws;
    bf16*  HTt   = (bf16*)w;   w += (size_t)OUTF * NN * 2;
    float* e1c   = (float*)w;  w += NN * 4;
    float* e2c   = (float*)w;  w += NN * 4;
    int*   flag  = (int*)w;    w += 256;
    bf16*  TT    = (bf16*)w;   w += (size_t)OUTF * INF_ * 2;
    float* numP  = (float*)w;  w += (size_t)JSPLIT * NN * OUTF * 4;
    float* denP  = (float*)w;

    gat_detect<<<1, 64, 0, stream>>>((const unsigned short*)d_in[0], flag);

    gat_tt<float, 1><<<OUTF, INF_, 0, stream>>>((const float*)d_in[2], flag, TT);
    gat_tt<bf16, 0><<<OUTF, INF_, 0, stream>>>((const bf16*)d_in[2], flag, TT);

    gat_proj_t<float, 1><<<NN / 32, 256, 0, stream>>>(
        (const float*)d_in[0], TT, (const float*)d_in[3], flag, HTt, e1c, e2c);
    gat_proj_t<bf16, 0><<<NN / 32, 256, 0, stream>>>(
        (const bf16*)d_in[0], TT, (const bf16*)d_in[3], flag, HTt, e1c, e2c);

    gat_attn<<<(NN / 64) * JSPLIT, 256, 0, stream>>>(adj, HTt, e1c, e2c, numP, denP);

    gat_fin<<<NN * OUTF / 4 / 256, 256, 0, stream>>>(numP, denP, flag, d_out);
}